// Round 10
// baseline (81.460 us; speedup 1.0000x reference)
//
#include <hip/hip_runtime.h>
#include <stdint.h>

typedef __bf16 bf16;
typedef bf16 bf16x8 __attribute__((ext_vector_type(8)));
typedef float floatx4 __attribute__((ext_vector_type(4)));

#define INV_T     2.0f                      // 1 / TEMPERATURE
#define SQRT_K    1.6986436206f             // sqrt(INV_T * log2(e))
#define INV_K     0.34657359028f            // ln(2)/2 = 1/(INV_T*log2(e))
#define GLOBAL_AS __attribute__((address_space(1)))
#define LDS_AS    __attribute__((address_space(3)))

// rep2 layout (16B chunks): chunk(r, ch) = (r>>6)*1024 + ch*64 + (r&63),
// ch = k>>3. MFMA A/B fragment loads and tile staging are fully coalesced,
// LDS fragment reads structurally conflict-free.

// MEASUREMENT LOG:
//  R14 probe: sim(256x256, 528 jobs, 2 blk/CU) = ~23us vs ~5-7us floor.
//  R15 (8 waves, 4/SIMD):   84.6 (-2.6)
//  R16 (128x128, 2080 jobs, 4 blk/CU): 81.6 (-3.0)
//  R17 (nrm grid-stride + split-vmcnt stage): 81.0 (-0.7, ~null) =>
//    intra-block scheduling exhausted.
//  R18: PERSISTENT blocks. 1024 blocks x 2-3 jobs. The rolling generation
//    turnover re-exposes each block's panel-stage cold start (~0.5us) ~2080
//    times; persistent blocks issue the NEXT panel's gload_lds + aF loads
//    under the CURRENT job's epilogue (aF regs dead by then), then one
//    vmcnt(0)+barrier. Also halves dispatch count. Raw s_barrier + asm
//    waitcnt (memory-clobber) pairs per the proven 8-phase template.

// ---------------------------------------------------------------------------
// Kernel 1: L2-normalize rows, scale by SQRT_K, write bf16 rep2 (swizzled).
// Grid-stride: 512 blocks x 4 iterations.
// ---------------------------------------------------------------------------
__global__ __launch_bounds__(256) void nrm_kernel(const float* __restrict__ p1,
                                                  const float* __restrict__ p2,
                                                  uint32_t* __restrict__ rep2,
                                                  float* __restrict__ out) {
    if (blockIdx.x == 0 && threadIdx.x == 0) *out = 0.0f;
    const int w    = threadIdx.x >> 6;
    const int lane = threadIdx.x & 63;
#pragma unroll
    for (int it = 0; it < 4; it++) {
        int row = it * 2048 + blockIdx.x * 4 + w;
        const float* srcRow = (row < 4096) ? (p1 + (size_t)row * 128)
                                           : (p2 + (size_t)(row - 4096) * 128);
        float2 v = ((const float2*)srcRow)[lane];
        float ss = v.x * v.x + v.y * v.y;
#pragma unroll
        for (int s = 1; s < 64; s <<= 1) ss += __shfl_xor(ss, s, 64);
        float inv = SQRT_K / fmaxf(sqrtf(ss), 1e-12f);
        union { bf16 h[2]; uint32_t u; } pk;
        pk.h[0] = (bf16)(v.x * inv);
        pk.h[1] = (bf16)(v.y * inv);
        int chunk = (row >> 6) * 1024 + (lane >> 2) * 64 + (row & 63);
        rep2[chunk * 4 + (lane & 3)] = pk.u;
    }
}

// ---------------------------------------------------------------------------
// Kernel 2: SYMMETRIC rowsum partials + positive-pair dot. 128x128 tiles.
// PERSISTENT: 1024 blocks; block b runs jobs {b, b+1024, b+2048 if <2080}.
// Each job decoded to upper-triangle (rb, cb), cb >= rb, rb,cb in [0,64).
// 256 threads = 4 waves; wave w owns 32 rows.
//   row partials (sum over its 128 cols)  -> rowsumP[row][cb]  (64 slots)
//   col partials (sum over its 128 rows)  -> rowsumP[col][rb]  (cb != rb)
// Partner tiles (cb == rb+32) write pos[i] / pos[i+4096] from strip diag.
// Per job: compute both passes (panel resident) -> lgkm+barrier (lB reads
// done, colPart visible) -> issue NEXT panel stage + NEXT aF loads ->
// epilogue (hides staging flight) -> vmcnt(0)+barrier -> next job.
// ---------------------------------------------------------------------------
__global__ __launch_bounds__(256, 4) void sim_kernel(const uint4* __restrict__ rep2,
                                                     float* __restrict__ rowsumP,
                                                     float* __restrict__ pos) {
    __shared__ uint4 lB[2048];          // 32 KB: 128-col x 128-k B panel
    __shared__ float colPart[4][128];   // 2 KB cross-wave colsum combine

    const int tid  = threadIdx.x;
    const int w    = tid >> 6;          // wave 0..3
    const int lane = tid & 63;
    const int quad = lane >> 4;
    const int lcol = lane & 15;

    // triangular decode: j -> (rb, cb), cb >= rb  (proven R16/R17)
    auto decode = [](int j, int& rb_, int& cb_) {
        int jpp = 2079 - j;
        int m = (int)((sqrtf((float)(8 * jpp + 1)) - 1.0f) * 0.5f);
        while ((m + 1) * (m + 2) / 2 <= jpp) ++m;   // exact integer fixup
        while (m * (m + 1) / 2 > jpp) --m;
        rb_ = 63 - m;
        cb_ = 63 - (jpp - m * (m + 1) / 2);
    };

    bf16x8 aF[2][4];
    // A fragments: rows rb*128 + w*32 + mi*16 + lcol, k = ks*32+quad*8..+7.
    // 64-group = rb*2 + (w>>1); in-group row = (w&1)*32 + mi*16 + lcol.
    auto load_aF = [&](int rb_) {
        const uint4* aG = rep2 + (size_t)(rb_ * 2 + (w >> 1)) * 1024;
#pragma unroll
        for (int mi = 0; mi < 2; mi++)
#pragma unroll
            for (int ks = 0; ks < 4; ks++)
                aF[mi][ks] = *(const bf16x8*)&aG[(ks * 4 + quad) * 64 + (w & 1) * 32 + mi * 16 + lcol];
    };
    // Stage B panel: rep2[cb*2048 .. +2048) uint4s, LDS dest linear in tid.
    auto stage = [&](int cb_) {
        const uint4* src = rep2 + (size_t)cb_ * 2048;
#pragma unroll
        for (int jj = 0; jj < 8; jj++)
            __builtin_amdgcn_global_load_lds(
                (const GLOBAL_AS uint32_t*)(src + jj * 256 + tid),
                (LDS_AS uint32_t*)&lB[jj * 256 + tid], 16, 0, 0);
    };

    int rb, cb;
    decode((int)blockIdx.x, rb, cb);
    load_aF(rb);
    stage(cb);
    asm volatile("s_waitcnt vmcnt(0)" ::: "memory");
    __builtin_amdgcn_s_barrier();       // panel in LDS, aF in regs

    for (int iter = 0; ; iter++) {
        const int wbase = rb * 128 + w * 32;       // wave's rows
        const int pbase = (wbase + 4096) & 8191;   // partner 32-col window

        float rs[8];
#pragma unroll
        for (int i = 0; i < 8; i++) rs[i] = 0.0f;

        // 8 subtiles, panel fully resident, no waits inside.
#pragma unroll
        for (int t = 0; t < 2; t++) {
#pragma unroll
            for (int so = 0; so < 4; so++) {
                bf16x8 bF[4];
#pragma unroll
                for (int ks = 0; ks < 4; ks++)
                    bF[ks] = *(const bf16x8*)&lB[t * 1024 + (ks * 4 + quad) * 64 + so * 16 + lcol];

                floatx4 acc[2];
                const floatx4 zf = {0.0f, 0.0f, 0.0f, 0.0f};
#pragma unroll
                for (int mi = 0; mi < 2; mi++) acc[mi] = zf;
#pragma unroll
                for (int ks = 0; ks < 4; ks++)
#pragma unroll
                    for (int mi = 0; mi < 2; mi++)
                        acc[mi] = __builtin_amdgcn_mfma_f32_16x16x32_bf16(
                            aF[mi][ks], bF[ks], acc[mi], 0, 0, 0);

                const int c0s  = cb * 128 + t * 64 + so * 16;
                const int gcol = c0s + lcol;
                const bool diagS = ((c0s & ~31) == wbase);   // rb==cb diag strip
                const bool partS = ((c0s & ~31) == pbase);   // cb==rb+32 strip
                float cs = 0.0f;                             // colsum partial
                if (diagS | partS) {
#pragma unroll
                    for (int mi = 0; mi < 2; mi++)
#pragma unroll
                        for (int r = 0; r < 4; r++) {
                            int grow = wbase + mi * 16 + quad * 4 + r;
                            float s = acc[mi][r];
                            if (partS && gcol == grow + 4096) {   // rb<32 here
                                float d = s * INV_K;              // raw dot
                                pos[grow] = d;
                                pos[grow + 4096] = d;
                            }
                            float e = __builtin_amdgcn_exp2f(s);
                            if (diagS && grow == gcol) e = 0.0f;  // mask j==i
                            rs[mi * 4 + r] += e;
                            cs += e;
                        }
                } else {
#pragma unroll
                    for (int mi = 0; mi < 2; mi++)
#pragma unroll
                        for (int r = 0; r < 4; r++) {
                            float e = __builtin_amdgcn_exp2f(acc[mi][r]);
                            rs[mi * 4 + r] += e;
                            cs += e;
                        }
                }
                // colsum over the wave's 32 rows: reduce across quads
                cs += __shfl_xor(cs, 16, 64);
                cs += __shfl_xor(cs, 32, 64);
                if (quad == 0) colPart[w][t * 64 + so * 16 + lcol] = cs;
            }
        }

        // All lB reads issued+consumed; colPart ds_writes drained; join.
        asm volatile("s_waitcnt lgkmcnt(0)" ::: "memory");
        __builtin_amdgcn_s_barrier();

        // Issue NEXT job's panel + aF under this job's epilogue (aF dead).
        const int nj = (int)blockIdx.x + 1024 * (iter + 1);
        const bool has_next = (nj < 2080);
        int nrb = 0, ncb = 0;
        if (has_next) {
            decode(nj, nrb, ncb);
            stage(ncb);
            load_aF(nrb);
        }

        // epilogue: row partials reduce across lane bits 0-3
#pragma unroll
        for (int s = 1; s < 16; s <<= 1)
#pragma unroll
            for (int k = 0; k < 8; k++) rs[k] += __shfl_xor(rs[k], s, 64);

        if (lcol == 0) {
#pragma unroll
            for (int k = 0; k < 8; k++) {
                int grow = wbase + (k >> 2) * 16 + quad * 4 + (k & 3);
                rowsumP[(size_t)grow * 64 + cb] = rs[k];   // slot cb (of 64)
            }
        }

        // col partials -> mirror rows' slot rb (skip self-tile). colPart
        // was made visible by the lgkm+barrier above.
        if (rb != cb && tid < 128) {
            float c = colPart[0][tid] + colPart[1][tid] + colPart[2][tid] + colPart[3][tid];
            rowsumP[(size_t)(cb * 128 + tid) * 64 + rb] = c;
        }

        if (!has_next) break;
        rb = nrb; cb = ncb;
        asm volatile("s_waitcnt vmcnt(0)" ::: "memory");   // panel' + aF' landed
        __builtin_amdgcn_s_barrier();
    }
}

// ---------------------------------------------------------------------------
// Kernel 3: loss = (1/8192) * sum_i [ log(sum_c rowsumP[i][c]) - 2*pos_i ]
// ---------------------------------------------------------------------------
__global__ __launch_bounds__(128) void fin_kernel(const float* __restrict__ rowsumP,
                                                  const float* __restrict__ pos,
                                                  float* __restrict__ out) {
    int row = blockIdx.x * 128 + threadIdx.x;
    const floatx4* rp = (const floatx4*)(rowsumP + (size_t)row * 64);
    float d = 0.0f;
#pragma unroll
    for (int j = 0; j < 16; j++) {
        floatx4 q = rp[j];
        d += (q[0] + q[1]) + (q[2] + q[3]);
    }
    float v = logf(d) - pos[row] * INV_T;
#pragma unroll
    for (int s = 1; s < 64; s <<= 1) v += __shfl_xor(v, s, 64);
    __shared__ float red[2];
    if ((threadIdx.x & 63) == 0) red[threadIdx.x >> 6] = v;
    __syncthreads();
    if (threadIdx.x == 0)
        atomicAdd(out, (red[0] + red[1]) * (1.0f / 8192.0f));
}

extern "C" void kernel_launch(void* const* d_in, const int* in_sizes, int n_in,
                              void* d_out, int out_size, void* d_ws, size_t ws_size,
                              hipStream_t stream) {
    const float* p1 = (const float*)d_in[0];
    const float* p2 = (const float*)d_in[1];
    float* out = (float*)d_out;

    char* ws       = (char*)d_ws;
    uint32_t* rep2 = (uint32_t*)ws;                             // 2 MB
    float* rowsumP = (float*)(ws + (2u << 20));                 // 2 MB (64 slots)
    float* pos     = (float*)(ws + (4u << 20));                 // 32 KB

    nrm_kernel<<<512, 256, 0, stream>>>(p1, p2, rep2, out);
    sim_kernel<<<1024, 256, 0, stream>>>((const uint4*)rep2, rowsumP, pos);
    fin_kernel<<<64, 128, 0, stream>>>(rowsumP, pos, out);
}